// Round 5
// baseline (265.503 us; speedup 1.0000x reference)
//
#include <hip/hip_runtime.h>
#include <math.h>

#define WAVE 64
constexpr int   CC      = 100;    // classes (fixed by problem)
constexpr int   MAXM    = 160;    // max thresholds per class (~0.05*P+1 ~= 132)
constexpr int   BUCKET  = 4096;   // per-class positive-score bucket capacity (P ~ 2621 +- 51)
constexpr int   LCAP    = 4096;   // per-block LDS compaction buffer (expected ~1300)
constexpr float LSMOOTH = 0.1f;
constexpr int   TILE    = 64;     // k1 rows per block
constexpr int   ZN      = 3 * CC + 8;   // zeroed counter block: cls_cnt|g_cnt|g_sum|done

// ---------------- K1: LDS-tiled softmax stats (+ counter zero-init by block 0) ----------------
__global__ __launch_bounds__(256) void k1_tile(
    const float* __restrict__ pred, const int* __restrict__ targets,
    const float* __restrict__ weight, float* __restrict__ L_out,
    float* __restrict__ pos_out, float* __restrict__ ce_partial,
    int* __restrict__ zero_blk, int N)
{
    __shared__ float tile[TILE * CC];      // 25.6 KB
    __shared__ int   ttgt[TILE];
    __shared__ float tL[TILE], tpos[TILE];
    __shared__ float cered[4];
    const int tid = threadIdx.x;
    const int r0  = blockIdx.x * TILE;

    if (blockIdx.x == 0)                   // later kernels read these post-boundary
        for (int i = tid; i < ZN; i += 256) zero_blk[i] = 0;

    // stage: 64 rows x 25 float4, fully coalesced
    const float4* src = (const float4*)(pred + (size_t)r0 * CC);
    #pragma unroll
    for (int t = tid; t < TILE * (CC / 4); t += 256)
        *((float4*)&tile[t * 4]) = src[t];
    if (tid < TILE) ttgt[tid] = targets[r0 + tid];
    __syncthreads();

    const int x = tid & 15;                // lane within 16-wide row group
    const int G = tid >> 4;                // group 0..15
    float w[7];
    #pragma unroll
    for (int j = 0; j < 7; ++j) {
        int c = x + 16 * j;
        w[j] = (c < CC) ? weight[c] : 0.0f;
    }
    float Wl = 0.0f;
    #pragma unroll
    for (int j = 0; j < 7; ++j) Wl += w[j];
    #pragma unroll
    for (int off = 1; off < 16; off <<= 1) Wl += __shfl_xor(Wl, off, 16);

    float ce_acc = 0.0f;
    #pragma unroll
    for (int rr = 0; rr < 4; ++rr) {
        const int r = G * 4 + rr;
        const float* rp = tile + r * CC;
        float v[7];
        #pragma unroll
        for (int j = 0; j < 7; ++j) {
            int c = x + 16 * j;
            v[j] = (c < CC) ? rp[c] : -INFINITY;
        }
        float vmax = v[0];
        #pragma unroll
        for (int j = 1; j < 7; ++j) vmax = fmaxf(vmax, v[j]);
        #pragma unroll
        for (int off = 1; off < 16; off <<= 1) vmax = fmaxf(vmax, __shfl_xor(vmax, off, 16));
        float z = 0.0f, ws = 0.0f;
        #pragma unroll
        for (int j = 0; j < 7; ++j) {
            int c = x + 16 * j;
            if (c < CC) { z += __expf(v[j] - vmax); ws += w[j] * v[j]; }
        }
        #pragma unroll
        for (int off = 1; off < 16; off <<= 1) {
            z  += __shfl_xor(z,  off, 16);
            ws += __shfl_xor(ws, off, 16);
        }
        float L = vmax + __logf(z);
        if (x == 0) {
            int t = ttgt[r];
            float pt = rp[t];
            tL[r] = L; tpos[r] = pt - L;
            ce_acc += -((1.0f - LSMOOTH) * weight[t] * (pt - L)
                        + (LSMOOTH / CC) * (ws - Wl * L));
        }
    }
    #pragma unroll
    for (int off = 32; off; off >>= 1) ce_acc += __shfl_xor(ce_acc, off, WAVE);
    if ((tid & 63) == 0) cered[tid >> 6] = ce_acc;
    __syncthreads();
    if (tid < TILE) {                          // coalesced output
        L_out[r0 + tid]   = tL[tid];
        pos_out[r0 + tid] = tpos[tid];
    }
    if (tid == 0)
        ce_partial[blockIdx.x] = cered[0] + cered[1] + cered[2] + cered[3];
}

// ------- K1b: counting scatter of positive scores into per-class buckets -------
// 256 blocks: ~25k with-return global atomics (4096-block fusion would recreate
// the round-2 atomic pileup: 190k+ contended RMWs with return values).
__global__ __launch_bounds__(256) void k1b_scatter(
    const int* __restrict__ targets, const float* __restrict__ pos,
    int* __restrict__ cls_cnt, float* __restrict__ bucket, int N)
{
    __shared__ int hist[CC];
    __shared__ int base[CC];
    __shared__ int loc[CC];
    const int tid = threadIdx.x;
    const int rowsPerBlock = N / gridDim.x;
    const int r0 = blockIdx.x * rowsPerBlock;
    const int r1 = r0 + rowsPerBlock;
    for (int c = tid; c < CC; c += blockDim.x) { hist[c] = 0; loc[c] = 0; }
    __syncthreads();
    for (int r = r0 + tid; r < r1; r += blockDim.x)
        atomicAdd(&hist[targets[r]], 1);
    __syncthreads();
    for (int c = tid; c < CC; c += blockDim.x)
        base[c] = (hist[c] > 0) ? atomicAdd(&cls_cnt[c], hist[c]) : 0;
    __syncthreads();
    for (int r = r0 + tid; r < r1; r += blockDim.x) {
        int c = targets[r];
        int idx = base[c] + atomicAdd(&loc[c], 1);
        if (idx < BUCKET) bucket[(size_t)c * BUCKET + idx] = pos[r];
    }
}

// --------- K2: per class, radix-select the m smallest positive scores ---------
__global__ __launch_bounds__(256) void k2_select(
    const float* __restrict__ bucket, const int* __restrict__ cls_cnt,
    float* __restrict__ u, int* __restrict__ m_arr, int* __restrict__ P_arr,
    float* __restrict__ wm_arr)
{
    __shared__ unsigned int keys[BUCKET];     // 16 KB
    __shared__ unsigned int hist[256];
    __shared__ unsigned int scan[256];
    __shared__ unsigned int sel[256];
    __shared__ unsigned int s_prefix;
    __shared__ int s_rank;
    __shared__ int cnt_lt;
    const int c   = blockIdx.x;
    const int tid = threadIdx.x;
    const int P = min(cls_cnt[c], BUCKET);
    double Kd = 0.95 * (double)P;
    int kf = (int)floor(Kd);
    int m = P - kf;
    if (m > MAXM) m = MAXM;
    if (m < 0) m = 0;
    if (tid == 0) {
        m_arr[c] = m; P_arr[c] = P;
        wm_arr[c] = (float)((double)(kf + 1) - Kd);   // fractional last-step weight
        s_prefix = 0; s_rank = m - 1; cnt_lt = 0;
    }
    // monotone float->uint key
    for (int i = tid; i < P; i += 256) {
        unsigned int b = __float_as_uint(bucket[(size_t)c * BUCKET + i]);
        keys[i] = (b & 0x80000000u) ? ~b : (b | 0x80000000u);
    }
    __syncthreads();
    if (m == 0) return;                                // uniform exit

    // 4 rounds of 8-bit MSB radix select; digit pick via parallel scan
    for (int shift = 24; shift >= 0; shift -= 8) {
        hist[tid] = 0;
        __syncthreads();
        unsigned int pref = s_prefix;
        for (int i = tid; i < P; i += 256) {
            unsigned int k = keys[i];
            bool match = (shift == 24) || ((k >> (shift + 8)) == pref);
            if (match) atomicAdd(&hist[(k >> shift) & 255u], 1u);
        }
        __syncthreads();
        scan[tid] = hist[tid];
        __syncthreads();
        for (int off = 1; off < 256; off <<= 1) {      // Hillis-Steele inclusive scan
            unsigned int add = (tid >= off) ? scan[tid - off] : 0u;
            __syncthreads();
            scan[tid] += add;
            __syncthreads();
        }
        int r = s_rank;
        unsigned int inc = scan[tid];
        unsigned int exc = inc - hist[tid];
        __syncthreads();
        if ((unsigned int)r >= exc && (unsigned int)r < inc) {   // unique thread
            s_rank   = r - (int)exc;
            s_prefix = (pref << 8) | (unsigned int)tid;
        }
        __syncthreads();
    }
    const unsigned int kth = s_prefix;

    for (int i = tid; i < P; i += 256) {
        unsigned int k = keys[i];
        if (k < kth) {
            int pslot = atomicAdd(&cnt_lt, 1);
            sel[pslot] = k;
        }
    }
    __syncthreads();
    const int nlt = cnt_lt;
    for (int j = nlt + tid; j < 256; j += 256) sel[j] = (j < m) ? kth : 0xFFFFFFFFu;
    __syncthreads();
    for (int kk = 2; kk <= 256; kk <<= 1) {            // bitonic sort 256 ascending
        for (int j = kk >> 1; j > 0; j >>= 1) {
            int i = tid, ixj = tid ^ j;
            if (ixj > i) {
                unsigned int a = sel[i], b = sel[ixj];
                bool up = ((i & kk) == 0);
                if ((a > b) == up) { sel[i] = b; sel[ixj] = a; }
            }
            __syncthreads();
        }
    }
    if (tid < m) {
        unsigned int k = sel[tid];
        unsigned int b = (k & 0x80000000u) ? (k & 0x7fffffffu) : ~k;
        u[c * MAXM + tid] = __uint_as_float(b);        // m smallest, ascending
    }
}

// branchless uniform upper_bound over uc[0..m): #{i : uc[i] <= key}
__device__ __forceinline__ int ubound(const float* uc, int m, float key, int maxidx) {
    int l = 0;
    #pragma unroll
    for (int s = 128; s; s >>= 1) {
        int p = l + s - 1;
        float val = uc[p < maxidx ? p : maxidx];
        l += ((p < m) && (val <= key)) ? s : 0;
    }
    return l;
}

// --------- K3: stream + compact + rank own entries + last-block finalize ---------
__global__ __launch_bounds__(256) void k3_fused(
    const float4* __restrict__ pred4, const float* __restrict__ L,
    const float* __restrict__ u, const int* __restrict__ m_arr,
    int* __restrict__ g_cnt, int* __restrict__ g_sum, int* __restrict__ done,
    const float* __restrict__ ce_partial, int nPartial,
    const float* __restrict__ weight, const int* __restrict__ P_arr,
    const float* __restrict__ wm_arr, float* __restrict__ out,
    int N, int total4)
{
    __shared__ float umax_s[CC];
    __shared__ int   sm[CC];
    __shared__ int   lcnt[CC], lsum[CC];
    __shared__ uint2 buf[LCAP];               // 32 KB
    __shared__ int   lc;
    __shared__ int   isLast;
    __shared__ double r1[256], r2[256], r3[256];   // finalize reduce (6 KB)
    const int tid = threadIdx.x;
    if (tid < CC) {
        int m = m_arr[tid];
        sm[tid] = m;
        umax_s[tid] = (m > 0) ? u[tid * MAXM + m - 1] : -INFINITY;
        lcnt[tid] = 0; lsum[tid] = 0;
    }
    if (tid == 0) lc = 0;
    __syncthreads();

    // ---- phase 1: stream pred, compact qualifiers to LDS ----
    const int stride = gridDim.x * blockDim.x;
    int i = blockIdx.x * blockDim.x + tid;
    int j = i % 25;                            // float4 col within row
    int n = i / 25;                            // row
    const int dj = stride % 25, dn = stride / 25;
    while (i < total4) {
        float4 v = pred4[i];
        float Ln = L[n];
        float4 um = *((const float4*)&umax_s[j * 4]);
        float s0 = v.x - Ln, s1 = v.y - Ln, s2 = v.z - Ln, s3 = v.w - Ln;
        #pragma unroll
        for (int q = 0; q < 4; ++q) {
            float sc = (q == 0) ? s0 : (q == 1) ? s1 : (q == 2) ? s2 : s3;
            float mx = (q == 0) ? um.x : (q == 1) ? um.y : (q == 2) ? um.z : um.w;
            if (sc < mx) {
                int c = j * 4 + q;
                int idx = atomicAdd(&lc, 1);
                if (idx < LCAP) {
                    buf[idx] = make_uint2((unsigned int)c, __float_as_uint(sc));
                } else {                       // overflow (never at ~1300 avg): inline exact
                    int m = sm[c];
                    int l = ubound(u + c * MAXM, m, sc, MAXM - 1);
                    atomicAdd(&lcnt[c], 1);
                    atomicAdd(&lsum[c], m - 1 - l);
                }
            }
        }
        i += stride; j += dj; n += dn;
        if (j >= 25) { j -= 25; n += 1; }
    }
    __syncthreads();

    // ---- phase 2: rank own compacted entries at full lane density ----
    const int cnt = min(lc, LCAP);
    for (int k = tid; k < cnt; k += 256) {
        uint2 e = buf[k];
        int c = (int)e.x;
        float key = __uint_as_float(e.y);
        int m = sm[c];
        int l = ubound(u + c * MAXM, m, key, MAXM - 1);   // L1/L2-hot 64 KB table
        atomicAdd(&lcnt[c], 1);
        atomicAdd(&lsum[c], m - 1 - l);
    }
    __syncthreads();
    for (int c = tid; c < CC; c += 256) {
        if (lcnt[c]) { atomicAdd(&g_cnt[c], lcnt[c]); atomicAdd(&g_sum[c], lsum[c]); }
    }

    // ---- phase 3: last block finalizes (ticket pattern) ----
    if (tid == 0) {
        __threadfence();
        int t = atomicAdd(done, 1);
        isLast = (t == (int)gridDim.x - 1);
    }
    __syncthreads();
    if (!isLast) return;
    __threadfence();

    double ce = 0.0;
    for (int k = tid; k < nPartial; k += 256) ce += (double)ce_partial[k];
    double p = 0.0, wsum = 0.0;
    for (int c = tid; c < CC; c += 256) {
        int P = P_arr[c], m = sm[c];
        double wgt = (double)weight[c];
        long long Nn = (long long)N - P;
        if (P > 0 && Nn > 0 && m > 0) {
            double wm = (double)wm_arr[c];
            // atomic-read for cross-XCD coherence of this kernel's atomics
            double S   = (double)atomicAdd(&g_sum[c], 0)
                       + wm * (double)atomicAdd(&g_cnt[c], 0);
            double sub = 0.5 * (double)(m - 1) * (double)(m - 2) + wm * (double)(m - 1);
            double pc  = (S - sub) / ((double)Nn * (double)P);
            if (pc < 0.0) pc = 0.0;
            p += pc * wgt;
        }
        wsum += wgt;
    }
    r1[tid] = ce; r2[tid] = p; r3[tid] = wsum;
    __syncthreads();
    for (int off = 128; off; off >>= 1) {
        if (tid < off) {
            r1[tid] += r1[tid + off];
            r2[tid] += r2[tid + off];
            r3[tid] += r3[tid + off];
        }
        __syncthreads();
    }
    if (tid == 0) {
        double ce_loss = r1[0] / (double)N;
        double avg = r2[0] / (r3[0] * 0.05);           // MAX_PAUC = R1-R0 = 0.05
        avg = fmin(fmax(avg, 0.0), 1.0);
        out[0] = (float)(0.5 * ce_loss + 0.5 * (1.0 - avg * avg));
    }
}

extern "C" void kernel_launch(void* const* d_in, const int* in_sizes, int n_in,
                              void* d_out, int out_size, void* d_ws, size_t ws_size,
                              hipStream_t stream) {
    (void)n_in; (void)out_size; (void)ws_size;
    const float* pred    = (const float*)d_in[0];
    const int*   targets = (const int*)d_in[1];
    const float* weight  = (const float*)d_in[2];
    float* out = (float*)d_out;
    const int N = in_sizes[1];

    const int K1_BLOCKS = N / TILE;                    // 4096
    char* base = (char*)d_ws;
    size_t off = 0;
    auto take = [&](size_t bytes) { char* q = base + off; off += (bytes + 15) & ~(size_t)15; return q; };
    float* L_ws       = (float*)take((size_t)N * 4);
    float* pos_ws     = (float*)take((size_t)N * 4);
    float* ce_partial = (float*)take((size_t)K1_BLOCKS * 4);
    float* u          = (float*)take((size_t)CC * MAXM * 4);
    int*   m_arr      = (int*)take(CC * 4);
    int*   P_arr      = (int*)take(CC * 4);
    float* wm_arr     = (float*)take(CC * 4);
    int*   zero_blk   = (int*)take(ZN * 4);            // cls_cnt|g_cnt|g_sum|done
    int*   cls_cnt  = zero_blk;
    int*   g_cnt    = zero_blk + CC;
    int*   g_sum    = zero_blk + 2 * CC;
    int*   done     = zero_blk + 3 * CC;
    float* bucket     = (float*)take((size_t)CC * BUCKET * 4);   // 1.6 MB

    k1_tile<<<K1_BLOCKS, 256, 0, stream>>>(pred, targets, weight, L_ws, pos_ws,
                                           ce_partial, zero_blk, N);
    k1b_scatter<<<256, 256, 0, stream>>>(targets, pos_ws, cls_cnt, bucket, N);
    k2_select<<<CC, 256, 0, stream>>>(bucket, cls_cnt, u, m_arr, P_arr, wm_arr);
    const int total4 = (int)((size_t)N * CC / 4);
    k3_fused<<<1024, 256, 0, stream>>>((const float4*)pred, L_ws, u, m_arr,
                                       g_cnt, g_sum, done, ce_partial, K1_BLOCKS,
                                       weight, P_arr, wm_arr, out, N, total4);
}